// Round 4
// baseline (795.126 us; speedup 1.0000x reference)
//
#include <hip/hip_runtime.h>

#define LOG2E 1.4426950408889634f
#define ATTN_SCALE 0.08838834764831843f   // 1/sqrt(128)

using bhalf8 = __attribute__((ext_vector_type(8))) short;  // 8 bf16 in 4 VGPRs
using f32x4  = __attribute__((ext_vector_type(4))) float;  // MFMA accumulator

// round-to-nearest-even fp32 -> bf16
__device__ __forceinline__ unsigned short f2bf(float f) {
  unsigned u = __float_as_uint(f);
  u += 0x7fffu + ((u >> 16) & 1u);
  return (unsigned short)(u >> 16);
}

// pack two fp32 -> bf16x2 (round-half-up) with one v_perm_b32
__device__ __forceinline__ unsigned pack_bf16_2(float lo, float hi) {
  unsigned a = __float_as_uint(lo) + 0x8000u;
  unsigned b = __float_as_uint(hi) + 0x8000u;
  return __builtin_amdgcn_perm(b, a, 0x07060302);  // D = {b.hi16, a.hi16}
}

// async global->LDS DMA, 16B per lane; lds dest = wave-uniform base + lane*16B
__device__ __forceinline__ void gl_lds16(const unsigned short* g, unsigned short* l) {
  __builtin_amdgcn_global_load_lds(
      (const __attribute__((address_space(1))) void*)g,
      (__attribute__((address_space(3))) void*)l, 16, 0, 0);
}

// ---------------- fused fp32 -> bf16 convert (x + 4 weights) ----------------
__global__ void cvt_all(const float* __restrict__ x,  const float* __restrict__ wq,
                        const float* __restrict__ wk, const float* __restrict__ wv,
                        const float* __restrict__ wp,
                        unsigned short* __restrict__ xb,  unsigned short* __restrict__ wqb,
                        unsigned short* __restrict__ wkb, unsigned short* __restrict__ wvb,
                        unsigned short* __restrict__ wpb) {
  int i = blockIdx.x * blockDim.x + threadIdx.x;   // float4 index, 8388608 total
  const int MEq = 4194304, EEq = 1048576;          // EEq = 2^20
  const float* src; unsigned short* dst; int off;
  if (i < MEq) { src = x; dst = xb; off = i; }
  else {
    int j = i - MEq; int w = j >> 20; off = j & (EEq - 1);
    src = (w == 0) ? wq : (w == 1) ? wk : (w == 2) ? wv : wp;
    dst = (w == 0) ? wqb : (w == 1) ? wkb : (w == 2) ? wvb : wpb;
  }
  float4 f = reinterpret_cast<const float4*>(src)[off];
  unsigned lo = (unsigned)f2bf(f.x) | ((unsigned)f2bf(f.y) << 16);
  unsigned hi = (unsigned)f2bf(f.z) | ((unsigned)f2bf(f.w) << 16);
  reinterpret_cast<uint2*>(dst)[off] = make_uint2(lo, hi);
}

// ---------------- fused QKV GEMM: C = x[M,K] * W^T, BK=64 (2 stacked 32-tiles) --
// sel = blockIdx.x>>4: 0->Q [b,h,s,d], 1->K [b,h,s,d], 2->V^T [b,h,d,s]
// LDS layout per half kk: base kk*4096 + r*32 + kc  (m97 bank pattern preserved)
__global__ __launch_bounds__(256) void gemm_qkv(
    const unsigned short* __restrict__ A,
    const unsigned short* __restrict__ Wq,
    const unsigned short* __restrict__ Wk,
    const unsigned short* __restrict__ Wv,
    unsigned short* __restrict__ Qo,
    unsigned short* __restrict__ Ko,
    unsigned short* __restrict__ Vto) {
  const int tid  = threadIdx.x;
  const int lane = tid & 63;
  const int wave = tid >> 6;
  const int quad = lane >> 4;
  const int c16  = lane & 15;
  const int wr = wave >> 1, wc = wave & 1;
  const int sel  = blockIdx.x >> 4;
  const int col0 = (blockIdx.x & 15) * 128;
  const int row0 = blockIdx.y * 128;
  const unsigned short* Bt = (sel == 0) ? Wq : (sel == 1) ? Wk : Wv;

  __shared__ __align__(16) unsigned short As[128 * 64];
  __shared__ __align__(16) unsigned short Bs[128 * 64];

  f32x4 acc[4][4];
#pragma unroll
  for (int i = 0; i < 4; i++)
#pragma unroll
    for (int j = 0; j < 4; j++)
#pragma unroll
      for (int r = 0; r < 4; r++) acc[i][j][r] = 0.0f;

  for (int k0 = 0; k0 < 2048; k0 += 64) {
    __syncthreads();
#pragma unroll
    for (int i = 0; i < 4; i++) {
      int chunk = i * 256 + tid;           // 0..1023
      int h  = chunk >> 9;                 // which 32-k half
      int c9 = chunk & 511;
      int r  = c9 >> 2, kc = (c9 & 3) << 3;
      const unsigned short* ga = A  + (size_t)(row0 + r) * 2048 + k0 + h * 32 + kc;
      const unsigned short* gb = Bt + (size_t)(col0 + r) * 2048 + k0 + h * 32 + kc;
      unsigned short* la = As + (i * 256 + wave * 64) * 8;   // wave-uniform dest
      unsigned short* lb = Bs + (i * 256 + wave * 64) * 8;
      gl_lds16(ga, la);
      gl_lds16(gb, lb);
    }
    __syncthreads();   // vmcnt(0) drain: all 8 DMAs visible
#pragma unroll
    for (int kk = 0; kk < 2; kk++) {
      bhalf8 af[4], bfg[4];
#pragma unroll
      for (int i = 0; i < 4; i++)
        af[i] = *reinterpret_cast<const bhalf8*>(As + kk * 4096 + (wr * 64 + i * 16 + c16) * 32 + quad * 8);
#pragma unroll
      for (int j = 0; j < 4; j++)
        bfg[j] = *reinterpret_cast<const bhalf8*>(Bs + kk * 4096 + (wc * 64 + j * 16 + c16) * 32 + quad * 8);
#pragma unroll
      for (int i = 0; i < 4; i++)
#pragma unroll
        for (int j = 0; j < 4; j++)
          acc[i][j] = __builtin_amdgcn_mfma_f32_16x16x32_bf16(af[i], bfg[j], acc[i][j], 0, 0, 0);
    }
  }

  if (sel < 2) {
    // Q/K: [b,h,s,d]; C layout col=c16, row=quad*4+r
    unsigned short* obf = (sel == 0) ? Qo : Ko;
#pragma unroll
    for (int i = 0; i < 4; i++)
#pragma unroll
      for (int j = 0; j < 4; j++)
#pragma unroll
        for (int r = 0; r < 4; r++) {
          int m = row0 + wr * 64 + i * 16 + quad * 4 + r;
          int n = col0 + wc * 64 + j * 16 + c16;
          int b = m >> 11, s = m & 2047;
          int h = n >> 7,  d = n & 127;
          obf[(((size_t)(b * 16 + h)) * 2048 + s) * 128 + d] = f2bf(acc[i][j][r]);
        }
  } else {
    // V^T: [b,h,d,s]; 4 consecutive r = 4 consecutive s -> 8B packed store
#pragma unroll
    for (int i = 0; i < 4; i++)
#pragma unroll
      for (int j = 0; j < 4; j++) {
        int m = row0 + wr * 64 + i * 16 + quad * 4;   // s base (mult of 4)
        int n = col0 + wc * 64 + j * 16 + c16;        // h*128+d
        int b = m >> 11, s = m & 2047;
        int h = n >> 7,  d = n & 127;
        uint2 pk = make_uint2(pack_bf16_2(acc[i][j][0], acc[i][j][1]),
                              pack_bf16_2(acc[i][j][2], acc[i][j][3]));
        *reinterpret_cast<uint2*>(Vto + (((size_t)(b * 16 + h)) * 128 + d) * 2048 + s) = pk;
      }
  }
}

// ---------------- output projection GEMM (fp32 out + bias), BK=64 ----------------
__global__ __launch_bounds__(256) void gemm_proj(
    const unsigned short* __restrict__ A,
    const unsigned short* __restrict__ Bt,
    float* __restrict__ of32, const float* __restrict__ bias) {
  const int tid  = threadIdx.x;
  const int lane = tid & 63;
  const int wave = tid >> 6;
  const int quad = lane >> 4;
  const int c16  = lane & 15;
  const int wr = wave >> 1, wc = wave & 1;
  const int row0 = blockIdx.y * 128;
  const int col0 = blockIdx.x * 128;

  __shared__ __align__(16) unsigned short As[128 * 64];
  __shared__ __align__(16) unsigned short Bs[128 * 64];

  f32x4 acc[4][4];
#pragma unroll
  for (int i = 0; i < 4; i++)
#pragma unroll
    for (int j = 0; j < 4; j++)
#pragma unroll
      for (int r = 0; r < 4; r++) acc[i][j][r] = 0.0f;

  for (int k0 = 0; k0 < 2048; k0 += 64) {
    __syncthreads();
#pragma unroll
    for (int i = 0; i < 4; i++) {
      int chunk = i * 256 + tid;
      int h  = chunk >> 9;
      int c9 = chunk & 511;
      int r  = c9 >> 2, kc = (c9 & 3) << 3;
      gl_lds16(A  + (size_t)(row0 + r) * 2048 + k0 + h * 32 + kc, As + (i * 256 + wave * 64) * 8);
      gl_lds16(Bt + (size_t)(col0 + r) * 2048 + k0 + h * 32 + kc, Bs + (i * 256 + wave * 64) * 8);
    }
    __syncthreads();
#pragma unroll
    for (int kk = 0; kk < 2; kk++) {
      bhalf8 af[4], bfg[4];
#pragma unroll
      for (int i = 0; i < 4; i++)
        af[i] = *reinterpret_cast<const bhalf8*>(As + kk * 4096 + (wr * 64 + i * 16 + c16) * 32 + quad * 8);
#pragma unroll
      for (int j = 0; j < 4; j++)
        bfg[j] = *reinterpret_cast<const bhalf8*>(Bs + kk * 4096 + (wc * 64 + j * 16 + c16) * 32 + quad * 8);
#pragma unroll
      for (int i = 0; i < 4; i++)
#pragma unroll
        for (int j = 0; j < 4; j++)
          acc[i][j] = __builtin_amdgcn_mfma_f32_16x16x32_bf16(af[i], bfg[j], acc[i][j], 0, 0, 0);
    }
  }

#pragma unroll
  for (int i = 0; i < 4; i++)
#pragma unroll
    for (int j = 0; j < 4; j++)
#pragma unroll
      for (int r = 0; r < 4; r++) {
        int m = row0 + wr * 64 + i * 16 + quad * 4 + r;
        int n = col0 + wc * 64 + j * 16 + c16;
        of32[(size_t)m * 2048 + n] = acc[i][j][r] + bias[n];
      }
}

// ---------------- flash attention: S^T formulation + prefetch + MFMA row-sum ----
#define LQK 136   // 128 + 8 pad
#define LV   72   // 64 + 8 pad
__global__ __launch_bounds__(256, 4) void flash_kernel(
    const unsigned short* __restrict__ Q,
    const unsigned short* __restrict__ K,
    const unsigned short* __restrict__ Vt,
    unsigned short* __restrict__ O) {
  const int tid  = threadIdx.x;
  const int lane = tid & 63;
  const int wave = tid >> 6;
  const int quad = lane >> 4;
  const int c16  = lane & 15;
  const int bh = blockIdx.x;
  const int q0 = (31 - blockIdx.y) * 64;     // longest-first
  const int bb = bh >> 4, hh = bh & 15;
  const int qidx = q0 + wave * 16 + c16;
  const float SL = ATTN_SCALE * LOG2E;

  __shared__ __align__(16) unsigned short Ks[64 * LQK];
  __shared__ __align__(16) unsigned short Vs[128 * LV];   // [d][t]

  const unsigned short* Kbh = K  + (size_t)bh * 2048 * 128;
  const unsigned short* Vbh = Vt + (size_t)bh * 128 * 2048;

  // preload K/V tile 0 into registers (overlaps Q staging below)
  bhalf8 rk[4], rv[4];
#pragma unroll
  for (int i = 0; i < 4; i++) {
    int chunk = i * 256 + tid;
    int t = chunk >> 4, dc = (chunk & 15) << 3;
    rk[i] = *reinterpret_cast<const bhalf8*>(Kbh + (size_t)t * 128 + dc);
    int d = chunk >> 3, tc = (chunk & 7) << 3;
    rv[i] = *reinterpret_cast<const bhalf8*>(Vbh + (size_t)d * 2048 + tc);
  }

  // stage Q tile into Ks (overlay), layout [t][d]
  const unsigned short* Qg = Q + ((size_t)bh * 2048 + q0) * 128;
#pragma unroll
  for (int i = 0; i < 4; i++) {
    int chunk = i * 256 + tid;
    int t = chunk >> 4, dc = (chunk & 15) << 3;
    *reinterpret_cast<bhalf8*>(Ks + t * LQK + dc) =
        *reinterpret_cast<const bhalf8*>(Qg + chunk * 8);
  }
  __syncthreads();
  bhalf8 qb[4];   // Q as B-operand: B[n=q=lane&15][k=quad*8+j]
#pragma unroll
  for (int kk = 0; kk < 4; kk++)
    qb[kk] = *reinterpret_cast<const bhalf8*>(Ks + (wave * 16 + c16) * LQK + kk * 32 + quad * 8);

  f32x4 o_acc[8];   // O^T: col q=c16, row d=jd*16+quad*4+r
#pragma unroll
  for (int jd = 0; jd < 8; jd++)
#pragma unroll
    for (int r = 0; r < 4; r++) o_acc[jd][r] = 0.0f;
  f32x4 lacc;       // MFMA row-sum accumulator: row 0 (quad0,reg0) = sum_t P
#pragma unroll
  for (int r = 0; r < 4; r++) lacc[r] = 0.0f;
  float m_i = -__builtin_inff();

  // ones A-frag: output row 0 = column sums (A[0][k]=1, A[m>0][k]=0)
  bhalf8 ones_a;
  {
    short v = (c16 == 0) ? (short)0x3F80 : (short)0;
#pragma unroll
    for (int e = 0; e < 8; e++) ones_a[e] = v;
  }

  const int nt = q0 / 64 + 1;
  for (int it = 0; it < nt; ++it) {
    const int t0 = it * 64;
    __syncthreads();   // previous tile's LDS reads complete
#pragma unroll
    for (int i = 0; i < 4; i++) {
      int chunk = i * 256 + tid;
      int t = chunk >> 4, dc = (chunk & 15) << 3;
      // rho(t): makes P land in B-frag order (k=8*quad+j)
      int row = (((t >> 5) << 1) | ((t >> 2) & 1)) * 16 + ((t >> 3) & 3) * 4 + (t & 3);
      *reinterpret_cast<bhalf8*>(Ks + row * LQK + dc) = rk[i];
      int d = chunk >> 3, tc = (chunk & 7) << 3;
      *reinterpret_cast<bhalf8*>(Vs + d * LV + tc) = rv[i];
    }
    __syncthreads();

    // prefetch next K/V tile: latency overlaps this tile's compute
    if (it + 1 < nt) {
      const int tn = t0 + 64;
#pragma unroll
      for (int i = 0; i < 4; i++) {
        int chunk = i * 256 + tid;
        int t = chunk >> 4, dc = (chunk & 15) << 3;
        rk[i] = *reinterpret_cast<const bhalf8*>(Kbh + (size_t)(tn + t) * 128 + dc);
        int d = chunk >> 3, tc = (chunk & 7) << 3;
        rv[i] = *reinterpret_cast<const bhalf8*>(Vbh + (size_t)d * 2048 + tn + tc);
      }
    }

    f32x4 st[4];
#pragma unroll
    for (int tt = 0; tt < 4; tt++) {
#pragma unroll
      for (int r = 0; r < 4; r++) st[tt][r] = 0.0f;
#pragma unroll
      for (int kk = 0; kk < 4; kk++) {
        bhalf8 ka = *reinterpret_cast<const bhalf8*>(Ks + (tt * 16 + c16) * LQK + kk * 32 + quad * 8);
        st[tt] = __builtin_amdgcn_mfma_f32_16x16x32_bf16(ka, qb[kk], st[tt], 0, 0, 0);
      }
    }

    const bool diag = (t0 == q0);
    float tmax = m_i;
#pragma unroll
    for (int tt = 0; tt < 4; tt++)
#pragma unroll
      for (int r = 0; r < 4; r++) {
        float x = st[tt][r] * SL;
        if (diag) {
          int t = t0 + ((tt >> 1) << 5) + (quad << 3) + ((tt & 1) << 2) + r;
          if (t > qidx) x = -__builtin_inff();
        }
        st[tt][r] = x;
        tmax = fmaxf(tmax, x);
      }
    tmax = fmaxf(tmax, __shfl_xor(tmax, 16));
    tmax = fmaxf(tmax, __shfl_xor(tmax, 32));
    unsigned long long anynew = __ballot(tmax > m_i);
    if (anynew) {                         // skip rescale when no max changed
      const float alpha = exp2f(m_i - tmax);
      m_i = tmax;
#pragma unroll
      for (int jd = 0; jd < 8; jd++)
#pragma unroll
        for (int r = 0; r < 4; r++) o_acc[jd][r] *= alpha;
      lacc[0] *= alpha;
    }
#pragma unroll
    for (int tt = 0; tt < 4; tt++)
#pragma unroll
      for (int r = 0; r < 4; r++)
        st[tt][r] = exp2f(st[tt][r] - m_i);   // P (0 for masked)

    // O^T += V^T * P^T ; row-sum via ones-row MFMA
#pragma unroll
    for (int u = 0; u < 2; u++) {
      union { bhalf8 h; uint4 w; } pu;
      pu.w.x = pack_bf16_2(st[2 * u][0],     st[2 * u][1]);
      pu.w.y = pack_bf16_2(st[2 * u][2],     st[2 * u][3]);
      pu.w.z = pack_bf16_2(st[2 * u + 1][0], st[2 * u + 1][1]);
      pu.w.w = pack_bf16_2(st[2 * u + 1][2], st[2 * u + 1][3]);
      lacc = __builtin_amdgcn_mfma_f32_16x16x32_bf16(ones_a, pu.h, lacc, 0, 0, 0);
#pragma unroll
      for (int jd = 0; jd < 8; jd++) {
        bhalf8 va = *reinterpret_cast<const bhalf8*>(Vs + (jd * 16 + c16) * LV + u * 32 + quad * 8);
        o_acc[jd] = __builtin_amdgcn_mfma_f32_16x16x32_bf16(va, pu.h, o_acc[jd], 0, 0, 0);
      }
    }
  }

  // l for this lane's column q=c16 lives in lane c16 (quad0), reg 0
  const float l = __shfl(lacc[0], c16);
  const float inv = 1.0f / l;
#pragma unroll
  for (int jd = 0; jd < 8; jd++) {
    unsigned lo = (unsigned)f2bf(o_acc[jd][0] * inv) | ((unsigned)f2bf(o_acc[jd][1] * inv) << 16);
    unsigned hi = (unsigned)f2bf(o_acc[jd][2] * inv) | ((unsigned)f2bf(o_acc[jd][3] * inv) << 16);
    *reinterpret_cast<uint2*>(O + ((size_t)(bb * 2048 + qidx)) * 2048 + hh * 128 + jd * 16 + quad * 4) =
        make_uint2(lo, hi);
  }
}

extern "C" void kernel_launch(void* const* d_in, const int* in_sizes, int n_in,
                              void* d_out, int out_size, void* d_ws, size_t ws_size,
                              hipStream_t stream) {
  const float* x  = (const float*)d_in[0];
  const float* wq = (const float*)d_in[1];
  const float* wk = (const float*)d_in[2];
  const float* wv = (const float*)d_in[3];
  const float* wp = (const float*)d_in[4];
  const float* bp = (const float*)d_in[5];
  float* out = (float*)d_out;

  unsigned short* ws  = (unsigned short*)d_ws;
  const size_t ME = (size_t)8192 * 2048;
  const size_t EE = (size_t)2048 * 2048;
  unsigned short* xb  = ws;
  unsigned short* wqb = xb  + ME;
  unsigned short* wkb = wqb + EE;
  unsigned short* wvb = wkb + EE;
  unsigned short* wpb = wvb + EE;
  unsigned short* Qb  = wpb + EE;          // [b,h,s,d]
  unsigned short* Kb  = Qb  + ME;          // [b,h,s,d]
  unsigned short* Vtb = Kb  + ME;          // [b,h,d,s]
  unsigned short* Ob  = Vtb + ME;          // [b,s,h*d]

  cvt_all<<<32768, 256, 0, stream>>>(x, wq, wk, wv, wp, xb, wqb, wkb, wvb, wpb);

  gemm_qkv<<<dim3(48, 64), 256, 0, stream>>>(xb, wqb, wkb, wvb, Qb, Kb, Vtb);

  flash_kernel<<<dim3(64, 32), 256, 0, stream>>>(Qb, Kb, Vtb, Ob);

  gemm_proj<<<dim3(16, 64), 256, 0, stream>>>(Ob, wpb, out, bp);
}